// Round 8
// baseline (271.215 us; speedup 1.0000x reference)
//
#include <hip/hip_runtime.h>
#include <math.h>

#define N_   325
#define BN_  10400
#define R_   32            // rows per block (2 M-tiles per wave); 10400/32 = 325 exact

typedef _Float16 h8v __attribute__((ext_vector_type(8)));  // 8 f16 (4 VGPRs)
typedef float    f4v __attribute__((ext_vector_type(4)));  // 4 fp32 acc

#define L1C  1.4426950408889634f    // log2(e)
#define L2C  2.8853900817779268f    // 2*log2(e)

__device__ __forceinline__ float rcp_f(float x){ return __builtin_amdgcn_rcpf(x); }
#if __has_builtin(__builtin_amdgcn_exp2f)
__device__ __forceinline__ float exp2_f(float x){ return __builtin_amdgcn_exp2f(x); }
#else
__device__ __forceinline__ float exp2_f(float x){ return __expf(x * 0.6931471805599453f); }
#endif

// h-plane [R_][64] f16, 16B blocks XOR-swizzled by row.
__device__ __forceinline__ int plane_idx(int m,int k){
    return m*64 + ((((k>>3)^(m&7))<<3)|(k&7));
}
__device__ __forceinline__ int frag_idx(int m,int kb){   // kb = k/8
    return m*64 + ((kb^(m&7))<<3);
}

// Load this lane's 24-VGPR B (Whh) fragment set, fp16.
__device__ __forceinline__ void load_B(const float* __restrict__ Whh, int jcol, int kg,
                                       h8v Bf[3][2])
{
#pragma unroll
    for (int g3=0; g3<3; ++g3)
#pragma unroll
        for (int ch=0; ch<2; ++ch) {
            const float* p = Whh + (g3*64 + jcol)*64 + ch*32 + kg*8;
            float4 a = *(const float4*)p;
            float4 b = *(const float4*)(p+4);
            h8v v;
            v[0]=(_Float16)a.x; v[1]=(_Float16)a.y; v[2]=(_Float16)a.z; v[3]=(_Float16)a.w;
            v[4]=(_Float16)b.x; v[5]=(_Float16)b.y; v[6]=(_Float16)b.z; v[7]=(_Float16)b.w;
            Bf[g3][ch] = v;
        }
}

// Block: 256 thr = 4 waves, 32 rows (2 M-tiles/wave), one cluster c.
// fp16 MFMA gh = h*Whh^T; fp32 carry in registers. Encoder input projection
// gi_r/gi_z folded into MFMA via a 3rd K-chunk (A-ext=[x0,x1,0..],
// B-ext=[ew0,ew1,0..] held by kg==0 lanes). Gate math via exp2 with -log2e
// pre-folded. h single fp16 plane, double-buffered (1 barrier/step).
// (256,4): slim fp16 footprint fits 128 unified regs -> 4 waves/SIMD.
__global__ void __launch_bounds__(256, 4) krnn_kernel(
    const float* __restrict__ X,
    const float* __restrict__ eWih, const float* __restrict__ eWhh,
    const float* __restrict__ ebih, const float* __restrict__ ebhh,
    const float* __restrict__ dWih, const float* __restrict__ dWhh,
    const float* __restrict__ dbih, const float* __restrict__ dbhh,
    const float* __restrict__ linW, const float* __restrict__ linb,
    const float* __restrict__ embed, float* __restrict__ out)
{
    __shared__ _Float16 sH[2][R_*64];                  // 8 KB
    __shared__ float2 sX2[12*R_];                      // [t][m] (x0,x1), 3 KB
    __shared__ float sWgt[R_];
    __shared__ float sVp[2][R_*4];                     // [buf][m][wv], 1 KB

    const int c    = blockIdx.y;
    const int row0 = blockIdx.x * R_;
    const int tid  = threadIdx.x;
    const int lane = tid & 63;
    const int wv   = tid >> 6;
    const int nl   = lane & 15;
    const int kg   = lane >> 4;
    const int jcol = wv*16 + nl;

    // ---------------- prologue ----------------
    for (int i = tid; i < 12*R_; i += 256) {           // sX2[t*R_+m]
        int t = i >> 5, m = i & (R_-1);
        const float* p = X + (size_t)(row0+m)*24 + 2*t;
        sX2[i] = make_float2(p[0], p[1]);
    }
    if (tid < R_) {
        int n = (row0 + tid) % N_;
        float e[10], mx = -1e30f;
#pragma unroll
        for (int cc=0; cc<10; ++cc){ e[cc]=embed[n*10+cc]; mx=fmaxf(mx,e[cc]); }
        float den = 0.0f;
#pragma unroll
        for (int cc=0; cc<10; ++cc) den += exp2_f((e[cc]-mx)*L1C);
        sWgt[tid] = exp2_f((e[c]-mx)*L1C) * rcp_f(den);
    }

    h8v Bf[3][2];
    load_B(eWhh + c*12288, jcol, kg, Bf);

    // encoder constants. r,z input-projection weights go to B-ext fp16 frags
    // (gi_r/gi_z computed by MFMA); biases stay pre-scaled by -L1C.
    float ew0_r, ew1_r, ew0_z, ew1_z;     // raw, for t=0 scalar path
    float ebss[2];                        // -L1C*(bih+bhh) for r,z
    float ew0n2, ew1n2, ebin2, ebh_n;     // n path
    {
        ew0_r = eWih[c*384 + jcol*2];       ew1_r = eWih[c*384 + jcol*2 + 1];
        ebss[0] = -L1C*(ebih[c*192 + jcol] + ebhh[c*192 + jcol]);
        int gc = 64 + jcol;
        ew0_z = eWih[c*384 + gc*2];         ew1_z = eWih[c*384 + gc*2 + 1];
        ebss[1] = -L1C*(ebih[c*192 + gc] + ebhh[c*192 + gc]);
        gc = 128 + jcol;
        ew0n2 = -L2C*eWih[c*384 + gc*2];    ew1n2 = -L2C*eWih[c*384 + gc*2 + 1];
        ebin2 = -L2C*ebih[c*192 + gc];
        ebh_n = ebhh[c*192 + gc];
    }
    // B-ext fragments: k=0 -> ew0, k=1 -> ew1 (kg==0 lanes only)
    h8v BeR, BeZ;
#pragma unroll
    for (int i=0;i<8;++i){ BeR[i]=(_Float16)0.0f; BeZ[i]=(_Float16)0.0f; }
    if (kg == 0) {
        BeR[0]=(_Float16)ew0_r; BeR[1]=(_Float16)ew1_r;
        BeZ[0]=(_Float16)ew0_z; BeZ[1]=(_Float16)ew1_z;
    }

    float hreg[2][4];                  // h_old (fp32 carry): rows Mt*16+kg*4+r4, col jcol
#pragma unroll
    for (int Mt=0;Mt<2;++Mt)
#pragma unroll
        for (int r4=0;r4<4;++r4) hreg[Mt][r4]=0.0f;

    __syncthreads();

    // ---------------- encoder t=0 (h=0, no MFMA), writes buf 0 ----------------
#pragma unroll
    for (int Mt=0; Mt<2; ++Mt)
#pragma unroll
        for (int r4=0; r4<4; ++r4) {
            int m = Mt*16 + kg*4 + r4;
            float2 x = sX2[m];         // t=0
            float r  = rcp_f(1.0f + exp2_f(fmaf(-L1C*ew0_r,x.x, fmaf(-L1C*ew1_r,x.y, ebss[0]))));
            float z  = rcp_f(1.0f + exp2_f(fmaf(-L1C*ew0_z,x.x, fmaf(-L1C*ew1_z,x.y, ebss[1]))));
            float gin2 = fmaf(ew0n2,x.x, fmaf(ew1n2,x.y, ebin2));
            float e  = exp2_f(fmaf(r*ebh_n, -L2C, gin2));
            float nn = fmaf(2.0f, rcp_f(1.0f + e), -1.0f);
            float hnew = nn - z*nn;
            hreg[Mt][r4] = hnew;
            sH[0][plane_idx(m,jcol)] = (_Float16)hnew;
        }
    __syncthreads();

    // ---------------- encoder steps 1..11: read buf (t+1)&1, write t&1 ----------------
    for (int t = 1; t < 12; ++t) {
        const int rp = (t+1)&1, wp = t&1;
        h8v Ah[2][2];
#pragma unroll
        for (int Mt=0; Mt<2; ++Mt)
#pragma unroll
            for (int ch=0; ch<2; ++ch)
                Ah[Mt][ch] = *(const h8v*)&sH[rp][frag_idx(Mt*16+nl, ch*4+kg)];

        // A-ext frags: [x0(row),x1(row),0..] for kg==0 lanes, row = Mt*16+nl
        h8v Ae[2];
#pragma unroll
        for (int Mt=0; Mt<2; ++Mt) {
#pragma unroll
            for (int i=0;i<8;++i) Ae[Mt][i] = (_Float16)0.0f;
            if (kg == 0) {
                float2 xe = sX2[t*R_ + Mt*16 + nl];
                Ae[Mt][0] = (_Float16)xe.x; Ae[Mt][1] = (_Float16)xe.y;
            }
        }

        f4v acc[2][3];
#pragma unroll
        for (int Mt=0;Mt<2;++Mt)
#pragma unroll
            for (int g3=0;g3<3;++g3)
#pragma unroll
                for (int r4=0;r4<4;++r4) acc[Mt][g3][r4]=0.0f;
#pragma unroll
        for (int Mt=0;Mt<2;++Mt) {
            acc[Mt][0] = __builtin_amdgcn_mfma_f32_16x16x32_f16(Ae[Mt], BeR, acc[Mt][0],0,0,0);
            acc[Mt][1] = __builtin_amdgcn_mfma_f32_16x16x32_f16(Ae[Mt], BeZ, acc[Mt][1],0,0,0);
#pragma unroll
            for (int g3=0;g3<3;++g3)
#pragma unroll
                for (int ch=0;ch<2;++ch)
                    acc[Mt][g3] = __builtin_amdgcn_mfma_f32_16x16x32_f16(Ah[Mt][ch], Bf[g3][ch], acc[Mt][g3],0,0,0);
        }

#pragma unroll
        for (int Mt=0;Mt<2;++Mt)
#pragma unroll
            for (int r4=0;r4<4;++r4) {
                int m = Mt*16 + kg*4 + r4;
                float2 x = sX2[t*R_ + m];
                float r  = rcp_f(1.0f + exp2_f(fmaf(acc[Mt][0][r4], -L1C, ebss[0])));
                float z  = rcp_f(1.0f + exp2_f(fmaf(acc[Mt][1][r4], -L1C, ebss[1])));
                float gin2 = fmaf(ew0n2,x.x, fmaf(ew1n2,x.y, ebin2));
                float q  = acc[Mt][2][r4] + ebh_n;
                float e  = exp2_f(fmaf(r*q, -L2C, gin2));
                float nn = fmaf(2.0f, rcp_f(1.0f + e), -1.0f);
                float hnew = nn + z*(hreg[Mt][r4] - nn);
                hreg[Mt][r4] = hnew;
                sH[wp][plane_idx(m,jcol)] = (_Float16)hnew;
            }
        __syncthreads();
    }

    // ---------------- decoder setup ----------------
    load_B(dWhh + c*12288, jcol, kg, Bf);
    float dws[2], dbss[2], dwn2, dbin2, dbh_n;
    {
        int gc = jcol;
        dws[0]  = -L1C*dWih[c*192 + gc];
        dbss[0] = -L1C*(dbih[c*192 + gc] + dbhh[c*192 + gc]);
        gc = 64 + jcol;
        dws[1]  = -L1C*dWih[c*192 + gc];
        dbss[1] = -L1C*(dbih[c*192 + gc] + dbhh[c*192 + gc]);
        gc = 128 + jcol;
        dwn2  = -L2C*dWih[c*192 + gc];
        dbin2 = -L2C*dbih[c*192 + gc];
        dbh_n = dbhh[c*192 + gc];
    }
    const float lwl = linW[c*64 + jcol];
    const float lb  = linb[c];

    float vlv[2][4];
#pragma unroll
    for (int Mt=0;Mt<2;++Mt)
#pragma unroll
        for (int r4=0;r4<4;++r4)
            vlv[Mt][r4] = sX2[11*R_ + Mt*16 + kg*4 + r4].x;   // last observed feature 0

    // ---------------- decoder: 12 steps, read buf (s+1)&1, write s&1 ----------------
    for (int s = 0; s < 12; ++s) {
        const int rp = (s+1)&1, wp = s&1;
        h8v Ah[2][2];
#pragma unroll
        for (int Mt=0; Mt<2; ++Mt)
#pragma unroll
            for (int ch=0; ch<2; ++ch)
                Ah[Mt][ch] = *(const h8v*)&sH[rp][frag_idx(Mt*16+nl, ch*4+kg)];

        f4v acc[2][3];
#pragma unroll
        for (int Mt=0;Mt<2;++Mt)
#pragma unroll
            for (int g3=0;g3<3;++g3)
#pragma unroll
                for (int r4=0;r4<4;++r4) acc[Mt][g3][r4]=0.0f;
#pragma unroll
        for (int Mt=0;Mt<2;++Mt)
#pragma unroll
            for (int g3=0;g3<3;++g3)
#pragma unroll
                for (int ch=0;ch<2;++ch)
                    acc[Mt][g3] = __builtin_amdgcn_mfma_f32_16x16x32_f16(Ah[Mt][ch], Bf[g3][ch], acc[Mt][g3],0,0,0);

#pragma unroll
        for (int Mt=0;Mt<2;++Mt)
#pragma unroll
            for (int r4=0;r4<4;++r4) {
                int m = Mt*16 + kg*4 + r4;
                float lv = vlv[Mt][r4];
                float r  = rcp_f(1.0f + exp2_f(fmaf(acc[Mt][0][r4], -L1C, fmaf(dws[0], lv, dbss[0]))));
                float z  = rcp_f(1.0f + exp2_f(fmaf(acc[Mt][1][r4], -L1C, fmaf(dws[1], lv, dbss[1]))));
                float q  = acc[Mt][2][r4] + dbh_n;
                float e  = exp2_f(fmaf(r*q, -L2C, fmaf(dwn2, lv, dbin2)));
                float nn = fmaf(2.0f, rcp_f(1.0f + e), -1.0f);
                float hnew = nn + z*(hreg[Mt][r4] - nn);
                hreg[Mt][r4] = hnew;
                sH[wp][plane_idx(m,jcol)] = (_Float16)hnew;

                float p = lwl * hnew;               // partial over this wave's 16 cols
                p += __shfl_xor(p, 1, 16);
                p += __shfl_xor(p, 2, 16);
                p += __shfl_xor(p, 4, 16);
                p += __shfl_xor(p, 8, 16);
                if (nl == 0) sVp[wp][m*4 + wv] = p;
            }
        __syncthreads();   // h plane + v partials ready (single barrier/step)

        // every lane redundantly finalizes v for its 8 rows (float4 broadcast reads)
#pragma unroll
        for (int Mt=0;Mt<2;++Mt)
#pragma unroll
            for (int r4=0;r4<4;++r4) {
                int m = Mt*16 + kg*4 + r4;
                float4 qv = *(const float4*)&sVp[wp][m*4];
                float v = (qv.x + qv.y) + (qv.z + qv.w) + lb;
                vlv[Mt][r4] = v;
                if (wv == 0 && nl == 0)
                    atomicAdd(&out[(size_t)(row0+m)*12 + s], sWgt[m]*v);
            }
        // sVp buffer alternates (wp) -> step s+2's writes can't race step s's reads
    }
}

extern "C" void kernel_launch(void* const* d_in, const int* in_sizes, int n_in,
                              void* d_out, int out_size, void* d_ws, size_t ws_size,
                              hipStream_t stream) {
    // 0:A 1:X 2:enc_Wih 3:enc_Whh 4:enc_bih 5:enc_bhh
    // 6:dec_Wih 7:dec_Whh 8:dec_bih 9:dec_bhh 10:lin_W 11:lin_b 12:embed
    const float* X    = (const float*)d_in[1];
    const float* eWih = (const float*)d_in[2];
    const float* eWhh = (const float*)d_in[3];
    const float* ebih = (const float*)d_in[4];
    const float* ebhh = (const float*)d_in[5];
    const float* dWih = (const float*)d_in[6];
    const float* dWhh = (const float*)d_in[7];
    const float* dbih = (const float*)d_in[8];
    const float* dbhh = (const float*)d_in[9];
    const float* linW = (const float*)d_in[10];
    const float* linb = (const float*)d_in[11];
    const float* emb  = (const float*)d_in[12];
    float* out = (float*)d_out;

    hipMemsetAsync(d_out, 0, (size_t)out_size * sizeof(float), stream);

    dim3 grid(BN_ / R_, 10);   // 325 x 10 blocks
    krnn_kernel<<<grid, dim3(256), 0, stream>>>(
        X, eWih, eWhh, ebih, ebhh, dWih, dWhh, dbih, dbhh, linW, linb, emb, out);
}

// Round 9
// 232.962 us; speedup vs baseline: 1.1642x; 1.1642x over previous
//
#include <hip/hip_runtime.h>
#include <math.h>

#define N_   325
#define BN_  10400
#define R_   32            // rows per block (2 M-tiles per wave); 10400/32 = 325 exact

typedef _Float16 h8v __attribute__((ext_vector_type(8)));  // 8 f16 (4 VGPRs)
typedef float    f4v __attribute__((ext_vector_type(4)));  // 4 fp32 acc

#define L1C  1.4426950408889634f    // log2(e)
#define L2C  2.8853900817779268f    // 2*log2(e)

__device__ __forceinline__ float rcp_f(float x){ return __builtin_amdgcn_rcpf(x); }
#if __has_builtin(__builtin_amdgcn_exp2f)
__device__ __forceinline__ float exp2_f(float x){ return __builtin_amdgcn_exp2f(x); }
#else
__device__ __forceinline__ float exp2_f(float x){ return __expf(x * 0.6931471805599453f); }
#endif

// h-plane [R_][64] f16, 16B blocks XOR-swizzled by row.
__device__ __forceinline__ int plane_idx(int m,int k){
    return m*64 + ((((k>>3)^(m&7))<<3)|(k&7));
}
__device__ __forceinline__ int frag_idx(int m,int kb){   // kb = k/8
    return m*64 + ((kb^(m&7))<<3);
}

// B (Whh) fragments, fp16, PRE-SCALED: r,z rows by -log2e; n rows by -2log2e.
// Folding the exp2 scale here deletes the per-element scale fma in the gates.
__device__ __forceinline__ void load_B_scaled(const float* __restrict__ Whh,
                                              int jcol, int kg, h8v Bf[3][2])
{
    const float sc[3] = { -L1C, -L1C, -L2C };
#pragma unroll
    for (int g3=0; g3<3; ++g3)
#pragma unroll
        for (int ch=0; ch<2; ++ch) {
            const float* p = Whh + (g3*64 + jcol)*64 + ch*32 + kg*8;
            float4 a = *(const float4*)p;
            float4 b = *(const float4*)(p+4);
            h8v v;
            v[0]=(_Float16)(sc[g3]*a.x); v[1]=(_Float16)(sc[g3]*a.y);
            v[2]=(_Float16)(sc[g3]*a.z); v[3]=(_Float16)(sc[g3]*a.w);
            v[4]=(_Float16)(sc[g3]*b.x); v[5]=(_Float16)(sc[g3]*b.y);
            v[6]=(_Float16)(sc[g3]*b.z); v[7]=(_Float16)(sc[g3]*b.w);
            Bf[g3][ch] = v;
        }
}

// Block: 256 thr = 4 waves, 32 rows (2 M-tiles/wave), one cluster c.
// Encoder: gi AND all biases folded into ext MFMAs (Ae=[x0,x1,1,0..] kg==0);
// gates are pure exp2/rcp. Decoder: lv = lin(h_{s-1}) computed by MFMA with
// B = linW replicated over n-cols (acc_v lands in the C-layout lanes that
// gate those rows) -> no shfl/sVp reduction; out[s-1] written during step s,
// v_11 via epilogue MFMA. Zero-C trick: first MFMA of each acc uses a shared
// zeroed C (D != C), removing per-step v_accvgpr_write zero-init.
__global__ void __launch_bounds__(256, 4) krnn_kernel(
    const float* __restrict__ X,
    const float* __restrict__ eWih, const float* __restrict__ eWhh,
    const float* __restrict__ ebih, const float* __restrict__ ebhh,
    const float* __restrict__ dWih, const float* __restrict__ dWhh,
    const float* __restrict__ dbih, const float* __restrict__ dbhh,
    const float* __restrict__ linW, const float* __restrict__ linb,
    const float* __restrict__ embed, float* __restrict__ out)
{
    __shared__ _Float16 sH[2][R_*64];                  // 8 KB
    __shared__ float2 sX2[12*R_];                      // [t][m] (x0,x1), 3 KB
    __shared__ float sWgt[R_];

    const int c    = blockIdx.y;
    const int row0 = blockIdx.x * R_;
    const int tid  = threadIdx.x;
    const int lane = tid & 63;
    const int wv   = tid >> 6;
    const int nl   = lane & 15;
    const int kg   = lane >> 4;
    const int jcol = wv*16 + nl;

    // ---------------- prologue ----------------
    for (int i = tid; i < 12*R_; i += 256) {           // sX2[t*R_+m]
        int t = i >> 5, m = i & (R_-1);
        const float* p = X + (size_t)(row0+m)*24 + 2*t;
        sX2[i] = make_float2(p[0], p[1]);
    }
    for (int i = tid; i < R_*64; i += 256) sH[1][i] = (_Float16)0.0f;  // h_{-1}=0
    if (tid < R_) {
        int n = (row0 + tid) % N_;
        float e[10], mx = -1e30f;
#pragma unroll
        for (int cc=0; cc<10; ++cc){ e[cc]=embed[n*10+cc]; mx=fmaxf(mx,e[cc]); }
        float den = 0.0f;
#pragma unroll
        for (int cc=0; cc<10; ++cc) den += exp2_f((e[cc]-mx)*L1C);
        sWgt[tid] = exp2_f((e[c]-mx)*L1C) * rcp_f(den);
    }

    h8v Bf[3][2];
    load_B_scaled(eWhh + c*12288, jcol, kg, Bf);

    // ext B-frags (kg==0 lanes hold k=0,1,2): weights AND biases, pre-scaled.
    h8v BeR, BeZ, BeN, BeN2;
#pragma unroll
    for (int i=0;i<8;++i){ BeR[i]=(_Float16)0.0f; BeZ[i]=(_Float16)0.0f;
                           BeN[i]=(_Float16)0.0f; BeN2[i]=(_Float16)0.0f; }
    if (kg == 0) {
        int gc = jcol;
        BeR[0]=(_Float16)(-L1C*eWih[c*384 + gc*2]);
        BeR[1]=(_Float16)(-L1C*eWih[c*384 + gc*2 + 1]);
        BeR[2]=(_Float16)(-L1C*(ebih[c*192+gc] + ebhh[c*192+gc]));
        gc = 64 + jcol;
        BeZ[0]=(_Float16)(-L1C*eWih[c*384 + gc*2]);
        BeZ[1]=(_Float16)(-L1C*eWih[c*384 + gc*2 + 1]);
        BeZ[2]=(_Float16)(-L1C*(ebih[c*192+gc] + ebhh[c*192+gc]));
        gc = 128 + jcol;
        BeN[0]=(_Float16)(-L2C*eWih[c*384 + gc*2]);
        BeN[1]=(_Float16)(-L2C*eWih[c*384 + gc*2 + 1]);
        BeN[2]=(_Float16)(-L2C*ebih[c*192+gc]);
        BeN2[2]=(_Float16)(-L2C*ebhh[c*192+gc]);
    }
    // A-ext: [x0,x1,1,0..] for kg==0 lanes; slots 0/1 updated per step.
    h8v Ae[2];
#pragma unroll
    for (int Mt=0;Mt<2;++Mt){
#pragma unroll
        for (int i=0;i<8;++i) Ae[Mt][i]=(_Float16)0.0f;
        if (kg==0) Ae[Mt][2]=(_Float16)1.0f;
    }

    const f4v Z0 = {0.0f,0.0f,0.0f,0.0f};   // shared zero C operand

    float hreg[2][4];
#pragma unroll
    for (int Mt=0;Mt<2;++Mt)
#pragma unroll
        for (int r4=0;r4<4;++r4) hreg[Mt][r4]=0.0f;

    __syncthreads();

    // ---------------- encoder steps 0..11 (t=0 uses zeroed plane) ----------------
    for (int t = 0; t < 12; ++t) {
        const int rp = (t+1)&1, wp = t&1;
        h8v Ah[2][2];
#pragma unroll
        for (int Mt=0; Mt<2; ++Mt)
#pragma unroll
            for (int ch=0; ch<2; ++ch)
                Ah[Mt][ch] = *(const h8v*)&sH[rp][frag_idx(Mt*16+nl, ch*4+kg)];

        if (kg == 0) {
#pragma unroll
            for (int Mt=0; Mt<2; ++Mt) {
                float2 xe = sX2[t*R_ + Mt*16 + nl];
                Ae[Mt][0] = (_Float16)xe.x; Ae[Mt][1] = (_Float16)xe.y;
            }
        }

        f4v a0[2], a1[2], a2[2], a3[2];
#pragma unroll
        for (int Mt=0;Mt<2;++Mt) {
            a0[Mt] = __builtin_amdgcn_mfma_f32_16x16x32_f16(Ae[Mt], BeR,  Z0, 0,0,0);
            a1[Mt] = __builtin_amdgcn_mfma_f32_16x16x32_f16(Ae[Mt], BeZ,  Z0, 0,0,0);
            a2[Mt] = __builtin_amdgcn_mfma_f32_16x16x32_f16(Ae[Mt], BeN2, Z0, 0,0,0);
            a3[Mt] = __builtin_amdgcn_mfma_f32_16x16x32_f16(Ae[Mt], BeN,  Z0, 0,0,0);
#pragma unroll
            for (int ch=0; ch<2; ++ch) {
                a0[Mt] = __builtin_amdgcn_mfma_f32_16x16x32_f16(Ah[Mt][ch], Bf[0][ch], a0[Mt],0,0,0);
                a1[Mt] = __builtin_amdgcn_mfma_f32_16x16x32_f16(Ah[Mt][ch], Bf[1][ch], a1[Mt],0,0,0);
                a2[Mt] = __builtin_amdgcn_mfma_f32_16x16x32_f16(Ah[Mt][ch], Bf[2][ch], a2[Mt],0,0,0);
            }
        }

#pragma unroll
        for (int Mt=0;Mt<2;++Mt)
#pragma unroll
            for (int r4=0;r4<4;++r4) {
                int m = Mt*16 + kg*4 + r4;
                float r  = rcp_f(1.0f + exp2_f(a0[Mt][r4]));   // arg fully in acc
                float z  = rcp_f(1.0f + exp2_f(a1[Mt][r4]));
                float e  = exp2_f(fmaf(r, a2[Mt][r4], a3[Mt][r4]));
                float nn = fmaf(2.0f, rcp_f(1.0f + e), -1.0f);
                float hnew = nn + z*(hreg[Mt][r4] - nn);
                hreg[Mt][r4] = hnew;
                sH[wp][plane_idx(m,jcol)] = (_Float16)hnew;
            }
        __syncthreads();
    }

    // ---------------- decoder setup ----------------
    load_B_scaled(dWhh + c*12288, jcol, kg, Bf);
    h8v Blw[2];                       // B = linW replicated over n-cols
#pragma unroll
    for (int ch=0; ch<2; ++ch) {
        const float* p = linW + c*64 + ch*32 + kg*8;
        float4 a = *(const float4*)p;
        float4 b = *(const float4*)(p+4);
        h8v v;
        v[0]=(_Float16)a.x; v[1]=(_Float16)a.y; v[2]=(_Float16)a.z; v[3]=(_Float16)a.w;
        v[4]=(_Float16)b.x; v[5]=(_Float16)b.y; v[6]=(_Float16)b.z; v[7]=(_Float16)b.w;
        Blw[ch] = v;
    }
    float dws0, ks0, dws1, ks1, dwn2, kn, cbh2;
    {
        int gc = jcol;
        dws0 = -L1C*dWih[c*192 + gc];
        ks0  = -L1C*(dbih[c*192 + gc] + dbhh[c*192 + gc]);
        gc = 64 + jcol;
        dws1 = -L1C*dWih[c*192 + gc];
        ks1  = -L1C*(dbih[c*192 + gc] + dbhh[c*192 + gc]);
        gc = 128 + jcol;
        dwn2 = -L2C*dWih[c*192 + gc];
        kn   = -L2C*dbih[c*192 + gc];
        cbh2 = -L2C*dbhh[c*192 + gc];
    }
    const float lb = linb[c];

    float lvx[2][4];                  // lv for s=0: last observed feature 0
#pragma unroll
    for (int Mt=0;Mt<2;++Mt)
#pragma unroll
        for (int r4=0;r4<4;++r4)
            lvx[Mt][r4] = sX2[11*R_ + Mt*16 + kg*4 + r4].x;

    // ---------------- decoder: 12 steps ----------------
    for (int s = 0; s < 12; ++s) {
        const int rp = (s+1)&1, wp = s&1;
        h8v Ah[2][2];
#pragma unroll
        for (int Mt=0; Mt<2; ++Mt)
#pragma unroll
            for (int ch=0; ch<2; ++ch)
                Ah[Mt][ch] = *(const h8v*)&sH[rp][frag_idx(Mt*16+nl, ch*4+kg)];

        f4v a0[2], a1[2], a2[2], av[2];
#pragma unroll
        for (int Mt=0;Mt<2;++Mt) {
            a0[Mt] = __builtin_amdgcn_mfma_f32_16x16x32_f16(Ah[Mt][0], Bf[0][0], Z0, 0,0,0);
            a1[Mt] = __builtin_amdgcn_mfma_f32_16x16x32_f16(Ah[Mt][0], Bf[1][0], Z0, 0,0,0);
            a2[Mt] = __builtin_amdgcn_mfma_f32_16x16x32_f16(Ah[Mt][0], Bf[2][0], Z0, 0,0,0);
            a0[Mt] = __builtin_amdgcn_mfma_f32_16x16x32_f16(Ah[Mt][1], Bf[0][1], a0[Mt],0,0,0);
            a1[Mt] = __builtin_amdgcn_mfma_f32_16x16x32_f16(Ah[Mt][1], Bf[1][1], a1[Mt],0,0,0);
            a2[Mt] = __builtin_amdgcn_mfma_f32_16x16x32_f16(Ah[Mt][1], Bf[2][1], a2[Mt],0,0,0);
        }
        if (s > 0) {
#pragma unroll
            for (int Mt=0;Mt<2;++Mt) {
                av[Mt] = __builtin_amdgcn_mfma_f32_16x16x32_f16(Ah[Mt][0], Blw[0], Z0, 0,0,0);
                av[Mt] = __builtin_amdgcn_mfma_f32_16x16x32_f16(Ah[Mt][1], Blw[1], av[Mt],0,0,0);
            }
        }

#pragma unroll
        for (int Mt=0;Mt<2;++Mt)
#pragma unroll
            for (int r4=0;r4<4;++r4) {
                int m = Mt*16 + kg*4 + r4;
                float lv;
                if (s == 0) lv = lvx[Mt][r4];
                else {
                    lv = av[Mt][r4] + lb;          // v_{s-1} = lin(h_{s-1})
                    if (wv == 0 && nl == 0)
                        atomicAdd(&out[(size_t)(row0+m)*12 + (s-1)], sWgt[m]*lv);
                }
                float r  = rcp_f(1.0f + exp2_f(a0[Mt][r4] + fmaf(dws0, lv, ks0)));
                float z  = rcp_f(1.0f + exp2_f(a1[Mt][r4] + fmaf(dws1, lv, ks1)));
                float e  = exp2_f(fmaf(r, a2[Mt][r4] + cbh2, fmaf(dwn2, lv, kn)));
                float nn = fmaf(2.0f, rcp_f(1.0f + e), -1.0f);
                float hnew = nn + z*(hreg[Mt][r4] - nn);
                hreg[Mt][r4] = hnew;
                sH[wp][plane_idx(m,jcol)] = (_Float16)hnew;
            }
        __syncthreads();
    }

    // ---------------- epilogue: v_11 from h_11 (buf (12+1)&1 = 1) ----------------
    {
        f4v av[2];
#pragma unroll
        for (int Mt=0; Mt<2; ++Mt) {
            h8v A0 = *(const h8v*)&sH[1][frag_idx(Mt*16+nl, 0*4+kg)];
            h8v A1 = *(const h8v*)&sH[1][frag_idx(Mt*16+nl, 1*4+kg)];
            av[Mt] = __builtin_amdgcn_mfma_f32_16x16x32_f16(A0, Blw[0], Z0, 0,0,0);
            av[Mt] = __builtin_amdgcn_mfma_f32_16x16x32_f16(A1, Blw[1], av[Mt],0,0,0);
        }
        if (wv == 0 && nl == 0) {
#pragma unroll
            for (int Mt=0;Mt<2;++Mt)
#pragma unroll
                for (int r4=0;r4<4;++r4) {
                    int m = Mt*16 + kg*4 + r4;
                    float v = av[Mt][r4] + lb;
                    atomicAdd(&out[(size_t)(row0+m)*12 + 11], sWgt[m]*v);
                }
        }
    }
}

extern "C" void kernel_launch(void* const* d_in, const int* in_sizes, int n_in,
                              void* d_out, int out_size, void* d_ws, size_t ws_size,
                              hipStream_t stream) {
    // 0:A 1:X 2:enc_Wih 3:enc_Whh 4:enc_bih 5:enc_bhh
    // 6:dec_Wih 7:dec_Whh 8:dec_bih 9:dec_bhh 10:lin_W 11:lin_b 12:embed
    const float* X    = (const float*)d_in[1];
    const float* eWih = (const float*)d_in[2];
    const float* eWhh = (const float*)d_in[3];
    const float* ebih = (const float*)d_in[4];
    const float* ebhh = (const float*)d_in[5];
    const float* dWih = (const float*)d_in[6];
    const float* dWhh = (const float*)d_in[7];
    const float* dbih = (const float*)d_in[8];
    const float* dbhh = (const float*)d_in[9];
    const float* linW = (const float*)d_in[10];
    const float* linb = (const float*)d_in[11];
    const float* emb  = (const float*)d_in[12];
    float* out = (float*)d_out;

    hipMemsetAsync(d_out, 0, (size_t)out_size * sizeof(float), stream);

    dim3 grid(BN_ / R_, 10);   // 325 x 10 blocks
    krnn_kernel<<<grid, dim3(256), 0, stream>>>(
        X, eWih, eWhh, ebih, ebhh, dWih, dWhh, dbih, dbhh, linW, linb, emb, out);
}